// Round 4
// baseline (323.501 us; speedup 1.0000x reference)
//
#include <hip/hip_runtime.h>

// EncoderDecoderLSTM on MI355X — R19: R18 base + PARTIAL-PIPELINE REBALANCE.
// stepB's 4-deep MFMA chain (Wih1*h0 then Whh1*h1) is the slot's long pole.
// A-waves already read the exact h0[t-1] fragments that partial(t-1) =
// b1 + Wih1*h0[t-1] needs -> A computes it one slot early (8 extra MFMAs,
// independent of A's act chain = fills A's stall window) and publishes f32
// partials to LDS (XOR-swizzled, 2-way = free). B seeds its Whh1 chain with
// the partial as MFMA C-operand: -8 MFMA issue, -2 chain levels, h0 reads
// dropped. Summation order unchanged -> BIT-EXACT (absmax must stay
// 0.0002441406). B lags A by 2 slots (+1 encoder slot). Decoder keeps the
// old 4-MFMA stepB (7 slots, trivial).
// Validated model (R16/R17/R18): chain ops ~6cyc, off-chain ~2cyc; chain
// cuts convert ~2x to time. R18 carryovers: chain-minimized act2, swapped
// MFMA D=W*h^T, b64 h-store, biasq via C-operand, lane-scalar x term.
// Skeleton: 512 thr, grid 256 (1 block/CU, 2 waves/SIMD), waves 0-3 layer0
// slot u / waves 4-7 layer1 t=u-2 (setprio(1) on B), one barrier/slot,
// static parity (unroll x2), h single f16 plane, single-f16 pre-scaled
// weights (1 MFMA/term), c fp32 in regs, xb prefetched across the barrier.

typedef _Float16 f16x8 __attribute__((ext_vector_type(8)));
typedef _Float16 f16x4 __attribute__((ext_vector_type(4)));
typedef float    f32x4 __attribute__((ext_vector_type(4)));
typedef float    f32x2 __attribute__((ext_vector_type(2)));

static constexpr int T_ENC = 365;
static constexpr int HZ    = 7;
static constexpr int BT    = 16;   // batch tile per block
static constexpr int HPAD  = 72;   // padded f16 row stride (144 B)

static constexpr float LOG2E  = 1.442695040888963f;
static constexpr float SCL_I  = -LOG2E;        // sigmoid gates: arg = -log2e * pre
static constexpr float SCL_G  = 2.0f * LOG2E;  // tanh gate:     arg = 2 log2e * pre

#if __has_builtin(__builtin_amdgcn_exp2f)
__device__ __forceinline__ float fexp2(float x) { return __builtin_amdgcn_exp2f(x); }
#else
__device__ __forceinline__ float fexp2(float x) { return __exp2f(x); }
#endif
#if __has_builtin(__builtin_amdgcn_rcpf)
__device__ __forceinline__ float frcp(float x) { return __builtin_amdgcn_rcpf(x); }
#else
__device__ __forceinline__ float frcp(float x) { return 1.0f / x; }
#endif

// acc += W * A^T : A-operand = weight fragment, B-operand = h fragment.
__device__ __forceinline__ f32x4 mm1(f16x8 w, f16x8 a, f32x4 acc) {
  return __builtin_amdgcn_mfma_f32_16x16x32_f16(w, a, acc, 0, 0, 0);
}

__global__ __launch_bounds__(512, 2)
void lstm_fused(const float* __restrict__ x,
                const float* __restrict__ eWih0, const float* __restrict__ eWhh0,
                const float* __restrict__ eb0,
                const float* __restrict__ eWih1, const float* __restrict__ eWhh1,
                const float* __restrict__ eb1,
                const float* __restrict__ dWih0, const float* __restrict__ dWhh0,
                const float* __restrict__ db0,
                const float* __restrict__ dWih1, const float* __restrict__ dWhh1,
                const float* __restrict__ db1,
                const float* __restrict__ fcW, const float* __restrict__ fcb,
                float* __restrict__ out)
{
  __shared__ __align__(16) float    xs[T_ENC * BT];                 // x transposed [t][b]
  __shared__ __align__(16) _Float16 h0s[2][BT * HPAD];              // h0, single f16 plane
  __shared__ __align__(16) _Float16 h1s[2][BT * HPAD];              // h1
  __shared__ __align__(16) float    pp[2][16 * 256];                // layer1 partials, swizzled
  __shared__ __align__(16) float    dins[BT];

  const int tid  = threadIdx.x;
  const int lane = tid & 63;
  const int wv   = tid >> 6;        // wave 0..7; 0-3 = layer0 group, 4-7 = layer1 group
  const int wg   = wv & 3;          // index within group
  const int n    = lane & 15;       // D col = batch row ; weight-fragment A-row
  const int q    = lane >> 4;       // quad: D rows 4q..4q+3 ; k-chunk for frags
  const int b0g  = blockIdx.x * BT;
  const int nH   = n * HPAD;
  const int cbase = (wg << 4) + (q << 2);   // hidden-col base this lane owns (4 units)
  // pp index: [n][rq ^ swz] — XOR swizzle spreads the 16-batch column across
  // bank quads; (n, n+8) collide 2-way = free. 16B alignment preserved.
  const int ppswz = (n & 7) << 2;
  const int ppn   = n << 8;

#if __has_builtin(__builtin_amdgcn_s_setprio)
  if (wv >= 4) __builtin_amdgcn_s_setprio(1);   // B = long pole per slot
#endif

  // Stage x[b][t] -> xs[t][b]
  for (int i = tid; i < T_ENC * BT; i += 512) {
    int b = i / T_ENC;
    int t = i - b * T_ENC;
    xs[t * BT + b] = x[(b0g + b) * T_ENC + t];
  }
  for (int i = tid; i < 2 * BT * HPAD; i += 512) {
    ((_Float16*)h0s)[i] = (_Float16)0.f;
    ((_Float16*)h1s)[i] = (_Float16)0.f;
  }
  if (tid < BT) dins[tid] = 0.f;

  // Weight registers (single f16 plane of the PRE-SCALED weight):
  //   ti: 0=i (-log2e), 1=f (-log2e), 2=g (+2log2e), 3=o (-log2e)
  //   group A: WA = Whh0 ; wih0q/biasq = Wih0/b0 (D-rows) ; WP = Wih1 ;
  //            biasqP = b1 (partial C-seed)
  //   group B: WB = Whh1 (encoder) ; WA = Wih1, biasq = b1 (decoder path)
  f16x8 WA[4][2], WB[4][2], WP[4][2];
  f32x4 biasq[4], wih0q[4], biasqP[4];

  auto gscale = [&](int ti) { return (ti == 2) ? SCL_G : SCL_I; };

  auto cvtrow = [&](const float* p, float s, f16x8& w) {
    #pragma unroll
    for (int j = 0; j < 8; ++j) w[j] = (_Float16)(p[j] * s);
  };
  auto loadA = [&](const float* Wih0_, const float* Whh0_, const float* b0_) {
    #pragma unroll
    for (int ti = 0; ti < 4; ++ti) {
      const float s = gscale(ti);
      const int rw = (ti * 4 + wg) * 16 + n;        // weight fragment row
      const int rq = (ti * 4 + wg) * 16 + (q << 2); // D-row base for bias/wih0
      #pragma unroll
      for (int rr = 0; rr < 4; ++rr) {
        biasq[ti][rr] = b0_[rq + rr] * s;
        wih0q[ti][rr] = Wih0_[rq + rr] * s;
      }
      #pragma unroll
      for (int kc = 0; kc < 2; ++kc)
        cvtrow(Whh0_ + rw * 64 + kc * 32 + q * 8, s, WA[ti][kc]);
    }
  };
  // A-side: layer1 input weights + bias for the partial product.
  auto loadAP = [&](const float* Wih1_, const float* b1_) {
    #pragma unroll
    for (int ti = 0; ti < 4; ++ti) {
      const float s = gscale(ti);
      const int rw = (ti * 4 + wg) * 16 + n;
      const int rq = (ti * 4 + wg) * 16 + (q << 2);
      #pragma unroll
      for (int rr = 0; rr < 4; ++rr) biasqP[ti][rr] = b1_[rq + rr] * s;
      #pragma unroll
      for (int kc = 0; kc < 2; ++kc)
        cvtrow(Wih1_ + rw * 64 + kc * 32 + q * 8, s, WP[ti][kc]);
    }
  };
  auto loadB = [&](const float* Wih1_, const float* Whh1_, const float* b1_) {
    #pragma unroll
    for (int ti = 0; ti < 4; ++ti) {
      const float s = gscale(ti);
      const int rw = (ti * 4 + wg) * 16 + n;
      const int rq = (ti * 4 + wg) * 16 + (q << 2);
      #pragma unroll
      for (int rr = 0; rr < 4; ++rr) biasq[ti][rr] = b1_[rq + rr] * s;
      #pragma unroll
      for (int kc = 0; kc < 2; ++kc) {
        cvtrow(Wih1_ + rw * 64 + kc * 32 + q * 8, s, WA[ti][kc]);
        cvtrow(Whh1_ + rw * 64 + kc * 32 + q * 8, s, WB[ti][kc]);
      }
    }
  };

  if (wv < 4) { loadA(eWih0, eWhh0, eb0); loadAP(eWih1, eb1); }
  else        loadB(eWih1, eWhh1, eb1);

  // c-state: lane owns (batch n, hidden cbase+0..3), pairs (0,1),(2,3).
  f32x2 cp[2] = {{0.f, 0.f}, {0.f, 0.f}};

  // Packed fused activation, chain-minimized (R18).
  auto act2 = [&](f32x2 a0, f32x2 a1, f32x2 a2, f32x2 a3, f32x2& c) -> f32x2 {
    f32x2 ei, ef, eg, eo;
    ei.x = fexp2(a0.x); ei.y = fexp2(a0.y);
    ef.x = fexp2(a1.x); ef.y = fexp2(a1.y);
    eg.x = fexp2(a2.x); eg.y = fexp2(a2.y);
    eo.x = fexp2(a3.x); eo.y = fexp2(a3.y);
    const f32x2 one = {1.f, 1.f};
    f32x2 di = one + ei, df = one + ef, dg = one + eg, dd = one + eo;
    f32x2 dif = di * df;
    f32x2 dic = di * c;
    f32x2 t1  = dif * dg;
    f32x2 nd  = eg * df - df;
    f32x2 pc  = dic * dg;
    f32x2 s   = pc + nd;
    const f32x2 sclg = {SCL_G, SCL_G};
    f32x2 sg  = sclg * s;
    f32x2 R1; R1.x = frcp(t1.x); R1.y = frcp(t1.y);
    c = R1 * s;
    f32x2 ca = R1 * sg;
    const f32x2 cap = {20.f, 20.f};
    ca.x = fminf(ca.x, cap.x); ca.y = fminf(ca.y, cap.y);
    f32x2 ec; ec.x = fexp2(ca.x); ec.y = fexp2(ca.y);
    f32x2 t2 = ec * dd + dd;
    f32x2 nc = ec - one;
    f32x2 R2; R2.x = frcp(t2.x); R2.y = frcp(t2.y);
    return nc * R2;
  };

  // Shared epilogue: act on 4 D-rows (2 packed pairs) + single b64 h publish.
  auto epilogue = [&](const f32x4* g, _Float16* O) {
    f32x2 h2[2];
    #pragma unroll
    for (int pr = 0; pr < 2; ++pr) {
      f32x2 a0 = {g[0][2 * pr], g[0][2 * pr + 1]};
      f32x2 a1 = {g[1][2 * pr], g[1][2 * pr + 1]};
      f32x2 a2 = {g[2][2 * pr], g[2][2 * pr + 1]};
      f32x2 a3 = {g[3][2 * pr], g[3][2 * pr + 1]};
      h2[pr] = act2(a0, a1, a2, a3, cp[pr]);
    }
    f16x4 hv;
    hv[0] = (_Float16)h2[0].x; hv[1] = (_Float16)h2[0].y;
    hv[2] = (_Float16)h2[1].x; hv[3] = (_Float16)h2[1].y;
    *(f16x4*)(O + nH + cbase) = hv;      // aligned 8B ds_write_b64
  };

  // layer0 step (plain; u=0 and decoder): D = bias + x(*)wih0 + Whh0*h0^T.
  auto stepA = [&](const _Float16* H, _Float16* O, float xb) {
    const _Float16* hp = H + nH;
    f16x8 a0 = *(const f16x8*)(hp + q * 8);
    f16x8 a1 = *(const f16x8*)(hp + 32 + q * 8);
    const f32x4 xbv = {xb, xb, xb, xb};
    f32x4 g[4];
    #pragma unroll
    for (int ti = 0; ti < 4; ++ti) {
      f32x4 ci = biasq[ti] + xbv * wih0q[ti];
      f32x4 a = mm1(WA[ti][0], a0, ci);
      a = mm1(WA[ti][1], a1, a);
      g[ti] = a;
    }
    epilogue(g, O);
  };

  // Encoder layer0 step + layer1 partial publish. stepA(u) reads h0[u-1]
  // fragments; partial(u-1) = b1 + Wih1*h0[u-1] reuses the SAME fragments.
  // Partial chain is independent of the act chain -> fills A's stall window.
  auto stepAP = [&](const _Float16* H, _Float16* O, float xb, float* ppb) {
    const _Float16* hp = H + nH;
    f16x8 a0 = *(const f16x8*)(hp + q * 8);
    f16x8 a1 = *(const f16x8*)(hp + 32 + q * 8);
    const f32x4 xbv = {xb, xb, xb, xb};
    f32x4 g[4];
    #pragma unroll
    for (int ti = 0; ti < 4; ++ti) {
      f32x4 ci = biasq[ti] + xbv * wih0q[ti];
      f32x4 a = mm1(WA[ti][0], a0, ci);
      a = mm1(WA[ti][1], a1, a);
      g[ti] = a;
    }
    #pragma unroll
    for (int ti = 0; ti < 4; ++ti) {
      f32x4 p = mm1(WP[ti][0], a0, biasqP[ti]);
      p = mm1(WP[ti][1], a1, p);
      const int rq = ((ti * 4 + wg) << 4) + (q << 2);
      *(f32x4*)&ppb[ppn + (rq ^ ppswz)] = p;   // swizzled b128 store
    }
    epilogue(g, O);
  };

  // Tail slot: partial(364) only (no stepA).
  auto partialOnly = [&](const _Float16* H, float* ppb) {
    const _Float16* hp = H + nH;
    f16x8 a0 = *(const f16x8*)(hp + q * 8);
    f16x8 a1 = *(const f16x8*)(hp + 32 + q * 8);
    #pragma unroll
    for (int ti = 0; ti < 4; ++ti) {
      f32x4 p = mm1(WP[ti][0], a0, biasqP[ti]);
      p = mm1(WP[ti][1], a1, p);
      const int rq = ((ti * 4 + wg) << 4) + (q << 2);
      *(f32x4*)&ppb[ppn + (rq ^ ppswz)] = p;
    }
  };

  // Encoder layer1 step: D = partial + Whh1 * h1^T. Chain depth 2.
  auto stepB_enc = [&](const _Float16* H1, const float* ppb, _Float16* O) {
    const _Float16* p1 = H1 + nH;
    f16x8 a0 = *(const f16x8*)(p1 + q * 8);
    f16x8 a1 = *(const f16x8*)(p1 + 32 + q * 8);
    f32x4 g[4];
    #pragma unroll
    for (int ti = 0; ti < 4; ++ti) {
      const int rq = ((ti * 4 + wg) << 4) + (q << 2);
      f32x4 ci = *(const f32x4*)&ppb[ppn + (rq ^ ppswz)];
      f32x4 a = mm1(WB[ti][0], a0, ci);
      a = mm1(WB[ti][1], a1, a);
      g[ti] = a;
    }
    epilogue(g, O);
  };

  // Full layer1 step (decoder): D = bias + Wih1*h0^T + Whh1*h1^T.
  auto stepB = [&](const _Float16* H0, const _Float16* H1, _Float16* O) {
    const _Float16* p0 = H0 + nH;
    const _Float16* p1 = H1 + nH;
    f16x8 b0 = *(const f16x8*)(p0 + q * 8);
    f16x8 b1 = *(const f16x8*)(p0 + 32 + q * 8);
    f16x8 a0 = *(const f16x8*)(p1 + q * 8);
    f16x8 a1 = *(const f16x8*)(p1 + 32 + q * 8);
    f32x4 g[4];
    #pragma unroll
    for (int ti = 0; ti < 4; ++ti) {
      f32x4 a = mm1(WA[ti][0], b0, biasq[ti]);
      a = mm1(WA[ti][1], b1, a);
      a = mm1(WB[ti][0], a0, a);
      a = mm1(WB[ti][1], a1, a);
      g[ti] = a;
    }
    epilogue(g, O);
  };

  __syncthreads();

  // ---- encoder ----
  // Slot u: A = stepA(t=u) + partial(t=u-1) -> pp[(u-1)&1];
  //         B = stepB(t=u-2) seeded from pp[u&1].
  // A reads h0[(u-1)&1], writes h0[u&1]; B reads h1[(u-1)&1], writes h1[u&1].
  float* pp0 = pp[0];
  float* pp1 = pp[1];

  float xb_next;
  // u = 0 (even): A only, no partial. h0[1] is zeros.
  if (wv < 4) {
    stepA(h0s[1], h0s[0], xs[n]);
    xb_next = xs[BT + n];               // prefetch u=1
  }
  __syncthreads();
  // u = 1 (odd): A stepA(1) + partial(0) -> pp[0]. B idle.
  if (wv < 4) {
    stepAP(h0s[0], h0s[1], xb_next, pp0);
    xb_next = xs[2 * BT + n];           // prefetch u=2
  }
  __syncthreads();

  // u = 2..363 as 181 (even, odd) pairs — both groups active.
  for (int s = 2; s <= 362; s += 2) {
    // slot s (even): A h0[1]->h0[0], partial->pp[1]; B h1[1]+pp[0] -> h1[0]
    if (wv < 4) {
      stepAP(h0s[1], h0s[0], xb_next, pp1);
      xb_next = xs[(s + 1) * BT + n];   // prefetch s+1
    } else {
      stepB_enc(h1s[1], pp0, h1s[0]);
    }
    __syncthreads();
    // slot s+1 (odd): A h0[0]->h0[1], partial->pp[0]; B h1[0]+pp[1] -> h1[1]
    if (wv < 4) {
      stepAP(h0s[0], h0s[1], xb_next, pp0);
      xb_next = xs[(s + 2) * BT + n];   // prefetch s+2 (<= 364)
    } else {
      stepB_enc(h1s[0], pp1, h1s[1]);
    }
    __syncthreads();
  }

  // u = 364 (even): A stepA(364) + partial(363)->pp[1]; B t=362.
  if (wv < 4) stepAP(h0s[1], h0s[0], xb_next, pp1);
  else        stepB_enc(h1s[1], pp0, h1s[0]);
  __syncthreads();
  // u = 365 (odd): A partial(364)->pp[0] only; B t=363.
  if (wv < 4) partialOnly(h0s[0], pp0);
  else        stepB_enc(h1s[0], pp1, h1s[1]);
  __syncthreads();
  // u = 366 (even): A loads decoder weights (idle slot); B t=364.
  if (wv < 4) loadA(dWih0, dWhh0, db0);
  else        stepB_enc(h1s[1], pp0, h1s[0]);
  __syncthreads();

  // ---- decoder ---- (latest h0, h1 live in parity-0 buffers)
  if (wv >= 4) loadB(dWih1, dWhh1, db1);
  float fcw[16];
  #pragma unroll
  for (int j = 0; j < 16; ++j) fcw[j] = fcW[q * 16 + j];
  const float fcb0 = fcb[0];

  #pragma unroll 1
  for (int hz = 0; hz < HZ; ++hz) {
    const int p = hz & 1;           // latest state parity at step entry
    if (wv < 4) {
      stepA(h0s[p], h0s[1 - p], dins[n]);
    }
    __syncthreads();
    if (wv >= 4) {
      stepB(h0s[1 - p], h1s[p], h1s[1 - p]);
    }
    __syncthreads();
    if (wv == 0) {
      const _Float16* Hh = h1s[1 - p];
      f16x8 hh0 = *(const f16x8*)(Hh + nH + q * 16);
      f16x8 hh1 = *(const f16x8*)(Hh + nH + q * 16 + 8);
      float pacc = 0.f;
      #pragma unroll
      for (int j = 0; j < 8; ++j) pacc += fcw[j] * (float)hh0[j];
      #pragma unroll
      for (int j = 0; j < 8; ++j) pacc += fcw[8 + j] * (float)hh1[j];
      pacc += __shfl_down(pacc, 32);
      pacc += __shfl_down(pacc, 16);
      if (lane < BT) {
        pacc += fcb0;
        out[(b0g + lane) * HZ + hz] = pacc;
        dins[lane] = pacc;
      }
    }
    __syncthreads();
  }
}

extern "C" void kernel_launch(void* const* d_in, const int* in_sizes, int n_in,
                              void* d_out, int out_size, void* d_ws, size_t ws_size,
                              hipStream_t stream) {
  (void)in_sizes; (void)n_in; (void)d_ws; (void)ws_size; (void)out_size;
  const float* x     = (const float*)d_in[0];
  const float* eWih0 = (const float*)d_in[1];
  const float* eWhh0 = (const float*)d_in[2];
  const float* eb0   = (const float*)d_in[3];
  const float* eWih1 = (const float*)d_in[4];
  const float* eWhh1 = (const float*)d_in[5];
  const float* eb1   = (const float*)d_in[6];
  const float* dWih0 = (const float*)d_in[7];
  const float* dWhh0 = (const float*)d_in[8];
  const float* db0   = (const float*)d_in[9];
  const float* dWih1 = (const float*)d_in[10];
  const float* dWhh1 = (const float*)d_in[11];
  const float* db1   = (const float*)d_in[12];
  const float* fcW   = (const float*)d_in[13];
  const float* fcb   = (const float*)d_in[14];
  float* out = (float*)d_out;

  dim3 grid(4096 / BT);   // 256 blocks = 1/CU
  dim3 block(512);        // 8 waves: 4 layer0 + 4 layer1
  hipLaunchKernelGGL(lstm_fused, grid, block, 0, stream,
                     x, eWih0, eWhh0, eb0, eWih1, eWhh1, eb1,
                     dWih0, dWhh0, db0, dWih1, dWhh1, db1, fcW, fcb, out);
}

// Round 5
// 312.587 us; speedup vs baseline: 1.0349x; 1.0349x over previous
//
#include <hip/hip_runtime.h>

// EncoderDecoderLSTM on MI355X — R20: producer/consumer split of layer1
// across a THIRD wave-group (12 waves, 3/SIMD — first occupancy raise).
// R19 post-mortem: A and B are balanced poles; moving the Wih1*h0 partial
// onto A made A the pole (+12us). Same bit-exact factorization, new home:
//   A  (wv0-3):  stepA, unchanged R18 (8 MFMA + act).
//   B2 (wv4-7):  h1 = act(pp + Whh1*h1) — pp as MFMA C-seed, 2-deep chain,
//                8 MFMA + act  (was 16 MFMA, 4-deep).
//   B1 (wv8-11): pp = b1 + Wih1*h0 — 8 MFMA + 4 b128 stores, NO act.
//                Pure slack at prio 0; fills A/B2 stall windows.
// VALU work/slot unchanged; waves/SIMD 2->3 (occupancy 23->34%) to fill
// the ~46% idle. Register aliasing keeps pressure flat: B1's Wih1 lives in
// B2's WX slot (disjoint roles), its b1 seed in biasq. +1 lag slot (367).
// Summation order identical to R18 -> BIT-EXACT (absmax 0.0002441406).
// Carryovers: chain-minimized act2 (R18), swapped MFMA D=W*h^T, b64
// h-store, bias via C-operand, lane-scalar x term (R17); hw exp/rcp (R16
// poly failed); one barrier/slot, static parity, h single f16 plane,
// pre-scaled single-f16 weights, c fp32 in regs, xb prefetch.

typedef _Float16 f16x8 __attribute__((ext_vector_type(8)));
typedef _Float16 f16x4 __attribute__((ext_vector_type(4)));
typedef float    f32x4 __attribute__((ext_vector_type(4)));
typedef float    f32x2 __attribute__((ext_vector_type(2)));

static constexpr int T_ENC = 365;
static constexpr int HZ    = 7;
static constexpr int BT    = 16;   // batch tile per block
static constexpr int HPAD  = 72;   // padded f16 row stride (144 B)

static constexpr float LOG2E  = 1.442695040888963f;
static constexpr float SCL_I  = -LOG2E;        // sigmoid gates: arg = -log2e * pre
static constexpr float SCL_G  = 2.0f * LOG2E;  // tanh gate:     arg = 2 log2e * pre

#if __has_builtin(__builtin_amdgcn_exp2f)
__device__ __forceinline__ float fexp2(float x) { return __builtin_amdgcn_exp2f(x); }
#else
__device__ __forceinline__ float fexp2(float x) { return __exp2f(x); }
#endif
#if __has_builtin(__builtin_amdgcn_rcpf)
__device__ __forceinline__ float frcp(float x) { return __builtin_amdgcn_rcpf(x); }
#else
__device__ __forceinline__ float frcp(float x) { return 1.0f / x; }
#endif

// acc += W * A^T : A-operand = weight fragment, B-operand = h fragment.
__device__ __forceinline__ f32x4 mm1(f16x8 w, f16x8 a, f32x4 acc) {
  return __builtin_amdgcn_mfma_f32_16x16x32_f16(w, a, acc, 0, 0, 0);
}

__global__ __launch_bounds__(768, 3)
void lstm_fused(const float* __restrict__ x,
                const float* __restrict__ eWih0, const float* __restrict__ eWhh0,
                const float* __restrict__ eb0,
                const float* __restrict__ eWih1, const float* __restrict__ eWhh1,
                const float* __restrict__ eb1,
                const float* __restrict__ dWih0, const float* __restrict__ dWhh0,
                const float* __restrict__ db0,
                const float* __restrict__ dWih1, const float* __restrict__ dWhh1,
                const float* __restrict__ db1,
                const float* __restrict__ fcW, const float* __restrict__ fcb,
                float* __restrict__ out)
{
  __shared__ __align__(16) float    xs[T_ENC * BT];                 // x transposed [t][b]
  __shared__ __align__(16) _Float16 h0s[2][BT * HPAD];              // h0, single f16 plane
  __shared__ __align__(16) _Float16 h1s[2][BT * HPAD];              // h1
  __shared__ __align__(16) float    pp[2][16 * 256];                // layer1 partials, swizzled
  __shared__ __align__(16) float    dins[BT];

  const int tid  = threadIdx.x;
  const int lane = tid & 63;
  const int wv   = tid >> 6;        // 0-3 A(layer0) | 4-7 B2(layer1 cons) | 8-11 B1(prod)
  const int wg   = wv & 3;          // index within group
  const int n    = lane & 15;       // D col = batch row ; weight-fragment A-row
  const int q    = lane >> 4;       // quad: D rows 4q..4q+3 ; k-chunk for frags
  const int b0g  = blockIdx.x * BT;
  const int nH   = n * HPAD;
  const int cbase = (wg << 4) + (q << 2);   // hidden-col base this lane owns (4 units)
  // pp index: [n][rq ^ swz] — XOR swizzle spreads the batch column across
  // bank quads; b128 ops hit the 8-quad BW floor. 16B alignment preserved.
  const int ppswz = (n & 7) << 2;
  const int ppn   = n << 8;

#if __has_builtin(__builtin_amdgcn_s_setprio)
  if (wv < 8) __builtin_amdgcn_s_setprio(1);   // A, B2 = poles; B1 slack at 0
#endif

  // Stage x[b][t] -> xs[t][b]
  for (int i = tid; i < T_ENC * BT; i += 768) {
    int b = i / T_ENC;
    int t = i - b * T_ENC;
    xs[t * BT + b] = x[(b0g + b) * T_ENC + t];
  }
  for (int i = tid; i < 2 * BT * HPAD; i += 768) {
    ((_Float16*)h0s)[i] = (_Float16)0.f;
    ((_Float16*)h1s)[i] = (_Float16)0.f;
  }
  if (tid < BT) dins[tid] = 0.f;

  // Weight registers (single f16 plane of the PRE-SCALED weight):
  //   ti: 0=i (-log2e), 1=f (-log2e), 2=g (+2log2e), 3=o (-log2e)
  //   A : WA=Whh0, biasq=b0, wih0q=Wih0 col  (loadA; dec weights at u=365)
  //   B2: WX=Whh1 (enc)      |  dec: WA=Wih1, WX=Whh1, biasq=b1 (loadB)
  //   B1: WX=Wih1, biasq=b1 C-seed (loadWP)  — aliases keep VGPR flat.
  f16x8 WA[4][2], WX[4][2];
  f32x4 biasq[4], wih0q[4];

  auto gscale = [&](int ti) { return (ti == 2) ? SCL_G : SCL_I; };

  auto cvtrow = [&](const float* p, float s, f16x8& w) {
    #pragma unroll
    for (int j = 0; j < 8; ++j) w[j] = (_Float16)(p[j] * s);
  };
  auto loadA = [&](const float* Wih0_, const float* Whh0_, const float* b0_) {
    #pragma unroll
    for (int ti = 0; ti < 4; ++ti) {
      const float s = gscale(ti);
      const int rw = (ti * 4 + wg) * 16 + n;        // weight fragment row
      const int rq = (ti * 4 + wg) * 16 + (q << 2); // D-row base for bias/wih0
      #pragma unroll
      for (int rr = 0; rr < 4; ++rr) {
        biasq[ti][rr] = b0_[rq + rr] * s;
        wih0q[ti][rr] = Wih0_[rq + rr] * s;
      }
      #pragma unroll
      for (int kc = 0; kc < 2; ++kc)
        cvtrow(Whh0_ + rw * 64 + kc * 32 + q * 8, s, WA[ti][kc]);
    }
  };
  auto loadWhh = [&](const float* Whh1_) {          // B2 encoder: WX only
    #pragma unroll
    for (int ti = 0; ti < 4; ++ti) {
      const float s = gscale(ti);
      const int rw = (ti * 4 + wg) * 16 + n;
      #pragma unroll
      for (int kc = 0; kc < 2; ++kc)
        cvtrow(Whh1_ + rw * 64 + kc * 32 + q * 8, s, WX[ti][kc]);
    }
  };
  auto loadWP = [&](const float* Wih1_, const float* b1_) {  // B1: WX + biasq
    #pragma unroll
    for (int ti = 0; ti < 4; ++ti) {
      const float s = gscale(ti);
      const int rw = (ti * 4 + wg) * 16 + n;
      const int rq = (ti * 4 + wg) * 16 + (q << 2);
      #pragma unroll
      for (int rr = 0; rr < 4; ++rr) biasq[ti][rr] = b1_[rq + rr] * s;
      #pragma unroll
      for (int kc = 0; kc < 2; ++kc)
        cvtrow(Wih1_ + rw * 64 + kc * 32 + q * 8, s, WX[ti][kc]);
    }
  };
  auto loadB = [&](const float* Wih1_, const float* Whh1_, const float* b1_) {
    #pragma unroll
    for (int ti = 0; ti < 4; ++ti) {
      const float s = gscale(ti);
      const int rw = (ti * 4 + wg) * 16 + n;
      const int rq = (ti * 4 + wg) * 16 + (q << 2);
      #pragma unroll
      for (int rr = 0; rr < 4; ++rr) biasq[ti][rr] = b1_[rq + rr] * s;
      #pragma unroll
      for (int kc = 0; kc < 2; ++kc) {
        cvtrow(Wih1_ + rw * 64 + kc * 32 + q * 8, s, WA[ti][kc]);
        cvtrow(Whh1_ + rw * 64 + kc * 32 + q * 8, s, WX[ti][kc]);
      }
    }
  };

  if (wv < 4)      loadA(eWih0, eWhh0, eb0);
  else if (wv < 8) loadWhh(eWhh1);
  else             loadWP(eWih1, eb1);

  // c-state: lane owns (batch n, hidden cbase+0..3), pairs (0,1),(2,3).
  f32x2 cp[2] = {{0.f, 0.f}, {0.f, 0.f}};

  // Packed fused activation, chain-minimized (R18).
  auto act2 = [&](f32x2 a0, f32x2 a1, f32x2 a2, f32x2 a3, f32x2& c) -> f32x2 {
    f32x2 ei, ef, eg, eo;
    ei.x = fexp2(a0.x); ei.y = fexp2(a0.y);
    ef.x = fexp2(a1.x); ef.y = fexp2(a1.y);
    eg.x = fexp2(a2.x); eg.y = fexp2(a2.y);
    eo.x = fexp2(a3.x); eo.y = fexp2(a3.y);
    const f32x2 one = {1.f, 1.f};
    f32x2 di = one + ei, df = one + ef, dg = one + eg, dd = one + eo;
    f32x2 dif = di * df;
    f32x2 dic = di * c;
    f32x2 t1  = dif * dg;
    f32x2 nd  = eg * df - df;
    f32x2 pc  = dic * dg;
    f32x2 s   = pc + nd;
    const f32x2 sclg = {SCL_G, SCL_G};
    f32x2 sg  = sclg * s;
    f32x2 R1; R1.x = frcp(t1.x); R1.y = frcp(t1.y);
    c = R1 * s;
    f32x2 ca = R1 * sg;
    const f32x2 cap = {20.f, 20.f};
    ca.x = fminf(ca.x, cap.x); ca.y = fminf(ca.y, cap.y);
    f32x2 ec; ec.x = fexp2(ca.x); ec.y = fexp2(ca.y);
    f32x2 t2 = ec * dd + dd;
    f32x2 nc = ec - one;
    f32x2 R2; R2.x = frcp(t2.x); R2.y = frcp(t2.y);
    return nc * R2;
  };

  // Shared epilogue: act on 4 D-rows (2 packed pairs) + single b64 h publish.
  auto epilogue = [&](const f32x4* g, _Float16* O) {
    f32x2 h2[2];
    #pragma unroll
    for (int pr = 0; pr < 2; ++pr) {
      f32x2 a0 = {g[0][2 * pr], g[0][2 * pr + 1]};
      f32x2 a1 = {g[1][2 * pr], g[1][2 * pr + 1]};
      f32x2 a2 = {g[2][2 * pr], g[2][2 * pr + 1]};
      f32x2 a3 = {g[3][2 * pr], g[3][2 * pr + 1]};
      h2[pr] = act2(a0, a1, a2, a3, cp[pr]);
    }
    f16x4 hv;
    hv[0] = (_Float16)h2[0].x; hv[1] = (_Float16)h2[0].y;
    hv[2] = (_Float16)h2[1].x; hv[3] = (_Float16)h2[1].y;
    *(f16x4*)(O + nH + cbase) = hv;      // aligned 8B ds_write_b64
  };

  // layer0 step: D = bias + x(*)wih0 + Whh0*h0^T.
  auto stepA = [&](const _Float16* H, _Float16* O, float xb) {
    const _Float16* hp = H + nH;
    f16x8 a0 = *(const f16x8*)(hp + q * 8);
    f16x8 a1 = *(const f16x8*)(hp + 32 + q * 8);
    const f32x4 xbv = {xb, xb, xb, xb};
    f32x4 g[4];
    #pragma unroll
    for (int ti = 0; ti < 4; ++ti) {
      f32x4 ci = biasq[ti] + xbv * wih0q[ti];
      f32x4 a = mm1(WA[ti][0], a0, ci);
      a = mm1(WA[ti][1], a1, a);
      g[ti] = a;
    }
    epilogue(g, O);
  };

  // B1 producer: pp = b1 + Wih1*h0^T -> LDS (no act, no chain tail).
  auto stepP = [&](const _Float16* H, float* ppb) {
    const _Float16* hp = H + nH;
    f16x8 a0 = *(const f16x8*)(hp + q * 8);
    f16x8 a1 = *(const f16x8*)(hp + 32 + q * 8);
    #pragma unroll
    for (int ti = 0; ti < 4; ++ti) {
      f32x4 p = mm1(WX[ti][0], a0, biasq[ti]);
      p = mm1(WX[ti][1], a1, p);
      const int rq = ((ti * 4 + wg) << 4) + (q << 2);
      *(f32x4*)&ppb[ppn + (rq ^ ppswz)] = p;   // swizzled b128 store
    }
  };

  // B2 consumer: D = pp + Whh1*h1^T. 2-deep MFMA chain.
  auto stepB2 = [&](const _Float16* H1, const float* ppb, _Float16* O) {
    const _Float16* p1 = H1 + nH;
    f16x8 a0 = *(const f16x8*)(p1 + q * 8);
    f16x8 a1 = *(const f16x8*)(p1 + 32 + q * 8);
    f32x4 g[4];
    #pragma unroll
    for (int ti = 0; ti < 4; ++ti) {
      const int rq = ((ti * 4 + wg) << 4) + (q << 2);
      f32x4 ci = *(const f32x4*)&ppb[ppn + (rq ^ ppswz)];
      f32x4 a = mm1(WX[ti][0], a0, ci);
      a = mm1(WX[ti][1], a1, a);
      g[ti] = a;
    }
    epilogue(g, O);
  };

  // Full layer1 step (decoder, wv4-7): D = bias + Wih1*h0^T + Whh1*h1^T.
  auto stepB = [&](const _Float16* H0, const _Float16* H1, _Float16* O) {
    const _Float16* p0 = H0 + nH;
    const _Float16* p1 = H1 + nH;
    f16x8 b0 = *(const f16x8*)(p0 + q * 8);
    f16x8 b1 = *(const f16x8*)(p0 + 32 + q * 8);
    f16x8 a0 = *(const f16x8*)(p1 + q * 8);
    f16x8 a1 = *(const f16x8*)(p1 + 32 + q * 8);
    f32x4 g[4];
    #pragma unroll
    for (int ti = 0; ti < 4; ++ti) {
      f32x4 a = mm1(WA[ti][0], b0, biasq[ti]);
      a = mm1(WA[ti][1], b1, a);
      a = mm1(WX[ti][0], a0, a);
      a = mm1(WX[ti][1], a1, a);
      g[ti] = a;
    }
    epilogue(g, O);
  };

  __syncthreads();

  // ---- encoder ----
  // Slot u: A t=u (h0[(u-1)&1] -> h0[u&1]);
  //         B1 t'=u-1 (reads h0[(u-1)&1], writes pp[(u-1)&1]);
  //         B2 t''=u-2 (reads pp[u&1], h1[(u-1)&1] -> h1[u&1]).
  float* pp0 = pp[0];
  float* pp1 = pp[1];

  float xb_next;
  // u = 0: A only. h0s[1] is zeros.
  if (wv < 4) {
    stepA(h0s[1], h0s[0], xs[n]);
    xb_next = xs[BT + n];               // prefetch u=1
  }
  __syncthreads();
  // u = 1: A t=1 (h0s[0]->h0s[1]); B1 t'=0 (h0s[0] -> pp[0]).
  if (wv < 4) {
    stepA(h0s[0], h0s[1], xb_next);
    xb_next = xs[2 * BT + n];           // prefetch u=2
  } else if (wv >= 8) {
    stepP(h0s[0], pp0);
  }
  __syncthreads();

  // u = 2..363 as 181 (even, odd) pairs — all three groups active.
  for (int u = 2; u <= 362; u += 2) {
    // even u: A h0s[1]->h0s[0]; B1 h0s[1]->pp[1]; B2 pp[0]+h1s[1]->h1s[0]
    if (wv < 4) {
      stepA(h0s[1], h0s[0], xb_next);
      xb_next = xs[(u + 1) * BT + n];   // prefetch u+1
    } else if (wv < 8) {
      stepB2(h1s[1], pp0, h1s[0]);
    } else {
      stepP(h0s[1], pp1);
    }
    __syncthreads();
    // odd u+1: A h0s[0]->h0s[1]; B1 h0s[0]->pp[0]; B2 pp[1]+h1s[0]->h1s[1]
    if (wv < 4) {
      stepA(h0s[0], h0s[1], xb_next);
      xb_next = xs[(u + 2) * BT + n];   // prefetch u+2 (<= 364)
    } else if (wv < 8) {
      stepB2(h1s[0], pp1, h1s[1]);
    } else {
      stepP(h0s[0], pp0);
    }
    __syncthreads();
  }

  // u = 364 (even): A t=364 (last); B1 t'=363; B2 t''=362.
  if (wv < 4)      stepA(h0s[1], h0s[0], xb_next);
  else if (wv < 8) stepB2(h1s[1], pp0, h1s[0]);
  else             stepP(h0s[1], pp1);
  __syncthreads();
  // u = 365 (odd): A idle -> decoder weights; B1 t'=364 (last); B2 t''=363.
  if (wv < 4)      loadA(dWih0, dWhh0, db0);
  else if (wv < 8) stepB2(h1s[0], pp1, h1s[1]);
  else             stepP(h0s[0], pp0);
  __syncthreads();
  // u = 366 (even): B2 t''=364 (last). Others idle.
  if (wv >= 4 && wv < 8) stepB2(h1s[1], pp0, h1s[0]);
  __syncthreads();

  // ---- decoder ---- (latest h0, h1 live in parity-0 buffers)
  if (wv >= 4 && wv < 8) loadB(dWih1, dWhh1, db1);
  float fcw[16];
  #pragma unroll
  for (int j = 0; j < 16; ++j) fcw[j] = fcW[q * 16 + j];
  const float fcb0 = fcb[0];

  #pragma unroll 1
  for (int hz = 0; hz < HZ; ++hz) {
    const int p = hz & 1;           // latest state parity at step entry
    if (wv < 4) {
      stepA(h0s[p], h0s[1 - p], dins[n]);
    }
    __syncthreads();
    if (wv >= 4 && wv < 8) {
      stepB(h0s[1 - p], h1s[p], h1s[1 - p]);
    }
    __syncthreads();
    if (wv == 0) {
      const _Float16* Hh = h1s[1 - p];
      f16x8 hh0 = *(const f16x8*)(Hh + nH + q * 16);
      f16x8 hh1 = *(const f16x8*)(Hh + nH + q * 16 + 8);
      float pacc = 0.f;
      #pragma unroll
      for (int j = 0; j < 8; ++j) pacc += fcw[j] * (float)hh0[j];
      #pragma unroll
      for (int j = 0; j < 8; ++j) pacc += fcw[8 + j] * (float)hh1[j];
      pacc += __shfl_down(pacc, 32);
      pacc += __shfl_down(pacc, 16);
      if (lane < BT) {
        pacc += fcb0;
        out[(b0g + lane) * HZ + hz] = pacc;
        dins[lane] = pacc;
      }
    }
    __syncthreads();
  }
}

extern "C" void kernel_launch(void* const* d_in, const int* in_sizes, int n_in,
                              void* d_out, int out_size, void* d_ws, size_t ws_size,
                              hipStream_t stream) {
  (void)in_sizes; (void)n_in; (void)d_ws; (void)ws_size; (void)out_size;
  const float* x     = (const float*)d_in[0];
  const float* eWih0 = (const float*)d_in[1];
  const float* eWhh0 = (const float*)d_in[2];
  const float* eb0   = (const float*)d_in[3];
  const float* eWih1 = (const float*)d_in[4];
  const float* eWhh1 = (const float*)d_in[5];
  const float* eb1   = (const float*)d_in[6];
  const float* dWih0 = (const float*)d_in[7];
  const float* dWhh0 = (const float*)d_in[8];
  const float* db0   = (const float*)d_in[9];
  const float* dWih1 = (const float*)d_in[10];
  const float* dWhh1 = (const float*)d_in[11];
  const float* db1   = (const float*)d_in[12];
  const float* fcW   = (const float*)d_in[13];
  const float* fcb   = (const float*)d_in[14];
  float* out = (float*)d_out;

  dim3 grid(4096 / BT);   // 256 blocks = 1/CU
  dim3 block(768);        // 12 waves: 4 A + 4 B2 + 4 B1 (3 waves/SIMD)
  hipLaunchKernelGGL(lstm_fused, grid, block, 0, stream,
                     x, eWih0, eWhh0, eb0, eWih1, eWhh1, eb1,
                     dWih0, dWhh0, db0, dWih1, dWhh1, db1, fcW, fcb, out);
}